// Round 1
// baseline (826.193 us; speedup 1.0000x reference)
//
#include <hip/hip_runtime.h>
#include <hip/hip_bf16.h>
#include <math.h>

constexpr int B = 64, S = 512, D = 768, H1 = 256, H2 = 128;
constexpr float THR = 0.1f;

// ---------------- K1a: logits L[b,i,j] = sum_k H[b,i,k]*H[b,j,k] ----------------
// 64x64 tile, TK=32, 256 threads, each thread 4x4. LDS stored transposed [k][row].
__global__ __launch_bounds__(256) void k_logits(const float* __restrict__ H,
                                                float* __restrict__ L) {
    const int b = blockIdx.z;
    const int i0 = blockIdx.x * 64;
    const int j0 = blockIdx.y * 64;
    const float* Hb = H + (size_t)b * S * D;

    __shared__ float As[32][68];  // [k][i]
    __shared__ float Bs[32][68];  // [k][j]

    const int tid = threadIdx.x;
    const int tx = tid & 15, ty = tid >> 4;
    float acc[4][4] = {};

    for (int k0 = 0; k0 < D; k0 += 32) {
        #pragma unroll
        for (int q = tid; q < 512; q += 256) {
            int r = q >> 3, c4 = (q & 7) << 2;
            float4 v = *(const float4*)(Hb + (size_t)(i0 + r) * D + k0 + c4);
            As[c4 + 0][r] = v.x; As[c4 + 1][r] = v.y;
            As[c4 + 2][r] = v.z; As[c4 + 3][r] = v.w;
        }
        #pragma unroll
        for (int q = tid; q < 512; q += 256) {
            int r = q >> 3, c4 = (q & 7) << 2;
            float4 v = *(const float4*)(Hb + (size_t)(j0 + r) * D + k0 + c4);
            Bs[c4 + 0][r] = v.x; Bs[c4 + 1][r] = v.y;
            Bs[c4 + 2][r] = v.z; Bs[c4 + 3][r] = v.w;
        }
        __syncthreads();
        #pragma unroll
        for (int k = 0; k < 32; ++k) {
            float a[4], bb[4];
            *(float4*)a  = *(const float4*)&As[k][ty * 4];
            *(float4*)bb = *(const float4*)&Bs[k][tx * 4];
            #pragma unroll
            for (int m = 0; m < 4; ++m)
                #pragma unroll
                for (int n = 0; n < 4; ++n)
                    acc[m][n] += a[m] * bb[n];
        }
        __syncthreads();
    }
    float* Lb = L + (size_t)b * S * S;
    #pragma unroll
    for (int m = 0; m < 4; ++m) {
        float4 v = make_float4(acc[m][0], acc[m][1], acc[m][2], acc[m][3]);
        *(float4*)(Lb + (size_t)(i0 + ty * 4 + m) * S + j0 + tx * 4) = v;
    }
}

// ---------------- K1b: in-place row softmax + threshold + self-loop -------------
__global__ __launch_bounds__(256) void k_softmax_thresh(float* __restrict__ A) {
    const int bi = blockIdx.x;          // b*S + i
    const int i = bi & (S - 1);
    float* row = A + (size_t)bi * S;
    const int tid = threadIdx.x;

    float2 v = *(float2*)(row + tid * 2);
    float mx = fmaxf(v.x, v.y);
    #pragma unroll
    for (int off = 32; off; off >>= 1) mx = fmaxf(mx, __shfl_xor(mx, off));
    __shared__ float redm[4], reds[4];
    const int lane = tid & 63, wv = tid >> 6;
    if (lane == 0) redm[wv] = mx;
    __syncthreads();
    mx = fmaxf(fmaxf(redm[0], redm[1]), fmaxf(redm[2], redm[3]));

    float e0 = __expf(v.x - mx), e1 = __expf(v.y - mx);
    float sm = e0 + e1;
    #pragma unroll
    for (int off = 32; off; off >>= 1) sm += __shfl_xor(sm, off);
    if (lane == 0) reds[wv] = sm;
    __syncthreads();
    sm = reds[0] + reds[1] + reds[2] + reds[3];
    const float inv = 1.0f / sm;

    float a0 = e0 * inv, a1 = e1 * inv;
    const int j0 = tid * 2, j1 = j0 + 1;
    a0 = (j0 == i) ? (a0 > THR ? a0 : 1.0f) : (a0 > THR ? a0 : 0.0f);
    a1 = (j1 == i) ? (a1 > THR ? a1 : 1.0f) : (a1 > THR ? a1 : 0.0f);
    *(float2*)(row + tid * 2) = make_float2(a0, a1);
}

// ---------------- K2: column sums -> dis = rsqrt(deg) ---------------------------
__global__ __launch_bounds__(256) void k_deg(const float* __restrict__ A,
                                             float* __restrict__ dis) {
    const int idx = blockIdx.x * 256 + threadIdx.x;  // b*S + j
    const int b = idx >> 9, j = idx & (S - 1);
    const float* Ab = A + (size_t)b * S * S + j;
    float deg = 0.f;
    for (int i = 0; i < S; ++i) deg += Ab[(size_t)i * S];
    dis[idx] = deg > 0.f ? rsqrtf(deg) : 0.f;
}

// ---------------- K2b: w[b,i] = dis_i * sum_j m_j*dis_j*A[i,j] ------------------
__global__ __launch_bounds__(256) void k_rowsum_w(const float* __restrict__ A,
                                                  const float* __restrict__ dis,
                                                  const int* __restrict__ mask,
                                                  float* __restrict__ w) {
    const int bi = blockIdx.x;
    const int b = bi >> 9;
    const float* row = A + (size_t)bi * S;
    const float* disb = dis + (b << 9);
    const int* mb = mask + (b << 9);
    const int tid = threadIdx.x;

    float2 a = *(const float2*)(row + tid * 2);
    const int j0 = tid * 2;
    float s = a.x * disb[j0] * (float)mb[j0] + a.y * disb[j0 + 1] * (float)mb[j0 + 1];
    #pragma unroll
    for (int off = 32; off; off >>= 1) s += __shfl_xor(s, off);
    __shared__ float red[4];
    if ((tid & 63) == 0) red[tid >> 6] = s;
    __syncthreads();
    if (tid == 0) w[bi] = (red[0] + red[1] + red[2] + red[3]) * dis[bi];
}

// ---------------- K3/K5: generic NN GEMM  C[r,c] = sum_k X[r,k] W[k,c] ----------
__global__ __launch_bounds__(256) void k_gemm_nn(const float* __restrict__ X,
                                                 const float* __restrict__ W,
                                                 float* __restrict__ C,
                                                 int K, int N) {
    const int r0 = blockIdx.x * 64;
    const int c0 = blockIdx.y * 64;

    __shared__ float Xs[32][68];  // [k][r]
    __shared__ float Ws[32][68];  // [k][c]

    const int tid = threadIdx.x;
    const int tx = tid & 15, ty = tid >> 4;
    float acc[4][4] = {};

    for (int k0 = 0; k0 < K; k0 += 32) {
        #pragma unroll
        for (int q = tid; q < 512; q += 256) {
            int r = q >> 3, c4 = (q & 7) << 2;
            float4 v = *(const float4*)(X + (size_t)(r0 + r) * K + k0 + c4);
            Xs[c4 + 0][r] = v.x; Xs[c4 + 1][r] = v.y;
            Xs[c4 + 2][r] = v.z; Xs[c4 + 3][r] = v.w;
        }
        #pragma unroll
        for (int q = tid; q < 512; q += 256) {
            int row = q >> 4, col4 = (q & 15) << 2;
            float4 v = *(const float4*)(W + (size_t)(k0 + row) * N + c0 + col4);
            *(float4*)&Ws[row][col4] = v;
        }
        __syncthreads();
        #pragma unroll
        for (int k = 0; k < 32; ++k) {
            float a[4], bb[4];
            *(float4*)a  = *(const float4*)&Xs[k][ty * 4];
            *(float4*)bb = *(const float4*)&Ws[k][tx * 4];
            #pragma unroll
            for (int m = 0; m < 4; ++m)
                #pragma unroll
                for (int n = 0; n < 4; ++n)
                    acc[m][n] += a[m] * bb[n];
        }
        __syncthreads();
    }
    #pragma unroll
    for (int m = 0; m < 4; ++m) {
        float4 v = make_float4(acc[m][0], acc[m][1], acc[m][2], acc[m][3]);
        *(float4*)(C + (size_t)(r0 + ty * 4 + m) * N + c0 + tx * 4) = v;
    }
}

// ---------------- K4: y1[b,j,h] = relu(dis_j * sum_i A[i,j]*dis_i*xw1[i,h] + b1) -
__global__ __launch_bounds__(256) void k_agg1(const float* __restrict__ A,
                                              const float* __restrict__ xw1,
                                              const float* __restrict__ dis,
                                              const float* __restrict__ b1,
                                              float* __restrict__ y1) {
    const int b = blockIdx.y;
    const int j0 = blockIdx.x * 16;
    const int h = threadIdx.x;  // 0..255
    const float* Ab = A + (size_t)b * S * S;
    const float* xb = xw1 + (size_t)b * S * H1;
    const float* disb = dis + b * S;

    __shared__ float As[16][16];  // [ii][jj], pre-scaled by dis_i
    float acc[16] = {};

    for (int ic = 0; ic < S; ic += 16) {
        const int li = threadIdx.x >> 4, lj = threadIdx.x & 15;
        As[li][lj] = Ab[(size_t)(ic + li) * S + j0 + lj] * disb[ic + li];
        __syncthreads();
        #pragma unroll
        for (int ii = 0; ii < 16; ++ii) {
            const float x = xb[(size_t)(ic + ii) * H1 + h];
            #pragma unroll
            for (int jj4 = 0; jj4 < 4; ++jj4) {
                float a[4];
                *(float4*)a = *(const float4*)&As[ii][jj4 * 4];
                acc[jj4 * 4 + 0] += a[0] * x;
                acc[jj4 * 4 + 1] += a[1] * x;
                acc[jj4 * 4 + 2] += a[2] * x;
                acc[jj4 * 4 + 3] += a[3] * x;
            }
        }
        __syncthreads();
    }
    const float bias = b1[h];
    #pragma unroll
    for (int jj = 0; jj < 16; ++jj) {
        float v = disb[j0 + jj] * acc[jj] + bias;
        y1[(size_t)b * S * H1 + (size_t)(j0 + jj) * H1 + h] = fmaxf(v, 0.f);
    }
}

// ---------------- K6: emb + head --------------------------------------------------
__global__ __launch_bounds__(128) void k_final(const float* __restrict__ xw2,
                                               const float* __restrict__ w,
                                               const int* __restrict__ mask,
                                               const float* __restrict__ b2,
                                               const float* __restrict__ Wc,
                                               const float* __restrict__ bc,
                                               float* __restrict__ out) {
    const int b = blockIdx.x;
    const int h = threadIdx.x;  // 0..127
    const float* xb = xw2 + (size_t)b * S * H2;
    const float* wb = w + b * S;
    const int* mb = mask + b * S;

    float acc = 0.f;
    for (int i = 0; i < S; ++i) acc += wb[i] * xb[(size_t)i * H2 + h];

    float msum = 0.f;
    for (int i = h; i < S; i += 128) msum += (float)mb[i];
    #pragma unroll
    for (int off = 32; off; off >>= 1) msum += __shfl_xor(msum, off);
    __shared__ float redm[2], redv[2];
    if ((h & 63) == 0) redm[h >> 6] = msum;
    __syncthreads();
    msum = redm[0] + redm[1];

    const float e = b2[h] + acc / msum;
    float val = e * Wc[h];
    #pragma unroll
    for (int off = 32; off; off >>= 1) val += __shfl_xor(val, off);
    if ((h & 63) == 0) redv[h >> 6] = val;
    __syncthreads();
    if (h == 0) {
        float z = redv[0] + redv[1] + bc[0];
        out[b] = 1.f / (1.f + expf(-z));
    }
}

extern "C" void kernel_launch(void* const* d_in, const int* in_sizes, int n_in,
                              void* d_out, int out_size, void* d_ws, size_t ws_size,
                              hipStream_t stream) {
    const float* H    = (const float*)d_in[0];
    const int*   mask = (const int*)d_in[1];
    const float* W1   = (const float*)d_in[2];
    const float* b1   = (const float*)d_in[3];
    const float* W2   = (const float*)d_in[4];
    const float* b2   = (const float*)d_in[5];
    const float* Wc   = (const float*)d_in[6];
    const float* bc   = (const float*)d_in[7];
    float* out = (float*)d_out;

    float* ws  = (float*)d_ws;
    float* A   = ws;                       // 16777216
    float* xw1 = ws + 16777216;            // 8388608
    float* y1  = ws + 25165824;            // 8388608
    float* xw2 = ws + 33554432;            // 4194304
    float* dis = ws + 37748736;            // 32768
    float* w   = ws + 37781504;            // 32768

    k_logits<<<dim3(S / 64, S / 64, B), 256, 0, stream>>>(H, A);
    k_softmax_thresh<<<B * S, 256, 0, stream>>>(A);
    k_deg<<<(B * S) / 256, 256, 0, stream>>>(A, dis);
    k_rowsum_w<<<B * S, 256, 0, stream>>>(A, dis, mask, w);
    k_gemm_nn<<<dim3((B * S) / 64, H1 / 64), 256, 0, stream>>>(H, W1, xw1, D, H1);
    k_agg1<<<dim3(S / 16, B), 256, 0, stream>>>(A, xw1, dis, b1, y1);
    k_gemm_nn<<<dim3((B * S) / 64, H2 / 64), 256, 0, stream>>>(y1, W2, xw2, H1, H2);
    k_final<<<B, 128, 0, stream>>>(xw2, w, mask, b2, Wc, bc, out);
}

// Round 2
// 207.873 us; speedup vs baseline: 3.9745x; 3.9745x over previous
//
#include <hip/hip_runtime.h>
#include <hip/hip_bf16.h>
#include <math.h>

constexpr int B = 64, S = 512, D = 768, H1 = 256, H2 = 128;
constexpr float THR = 0.1f;

typedef short bf16x8 __attribute__((ext_vector_type(8)));
typedef float f32x4 __attribute__((ext_vector_type(4)));
typedef unsigned int uint_t;
typedef const __attribute__((address_space(1))) unsigned int* gptr_t;
typedef __attribute__((address_space(3))) unsigned int* lptr_t;

__device__ __forceinline__ unsigned short f2bf(float f) {
    unsigned int u = __builtin_bit_cast(unsigned int, f);
    unsigned int r = (u + 0x7FFFu + ((u >> 16) & 1u)) >> 16;
    return (unsigned short)r;
}
__device__ __forceinline__ float bf2f(unsigned short b) {
    return __builtin_bit_cast(float, (unsigned int)b << 16);
}
__device__ __forceinline__ void unpack8(const uint4& r, float* v) {
    v[0] = __builtin_bit_cast(float, r.x << 16); v[1] = __builtin_bit_cast(float, r.x & 0xFFFF0000u);
    v[2] = __builtin_bit_cast(float, r.y << 16); v[3] = __builtin_bit_cast(float, r.y & 0xFFFF0000u);
    v[4] = __builtin_bit_cast(float, r.z << 16); v[5] = __builtin_bit_cast(float, r.z & 0xFFFF0000u);
    v[6] = __builtin_bit_cast(float, r.w << 16); v[7] = __builtin_bit_cast(float, r.w & 0xFFFF0000u);
}
__device__ __forceinline__ void gl2lds16(const void* g, void* l) {
    __builtin_amdgcn_global_load_lds((gptr_t)g, (lptr_t)l, 16, 0, 0);
}

// ---------------- cast H fp32 -> bf16 (row-major [tok][D]) ----------------
__global__ __launch_bounds__(256) void k_cast(const float* __restrict__ in,
                                              short* __restrict__ out, int n8) {
    for (int i = blockIdx.x * 256 + threadIdx.x; i < n8; i += gridDim.x * 256) {
        float4 a = ((const float4*)in)[i * 2];
        float4 b = ((const float4*)in)[i * 2 + 1];
        uint4 o;
        o.x = (uint_t)f2bf(a.x) | ((uint_t)f2bf(a.y) << 16);
        o.y = (uint_t)f2bf(a.z) | ((uint_t)f2bf(a.w) << 16);
        o.z = (uint_t)f2bf(b.x) | ((uint_t)f2bf(b.y) << 16);
        o.w = (uint_t)f2bf(b.z) | ((uint_t)f2bf(b.w) << 16);
        ((uint4*)out)[i] = o;
    }
}

// ---------------- cast + transpose weights: in[K][N] -> out[N][K] bf16 ----------
__global__ __launch_bounds__(256) void k_castT(const float* __restrict__ in,
                                               short* __restrict__ out, int Kd, int Nd) {
    int idx = blockIdx.x * 256 + threadIdx.x;
    if (idx >= Kd * Nd) return;
    int n = idx / Kd, k = idx - n * Kd;
    out[idx] = (short)f2bf(in[(size_t)k * Nd + n]);
}

// ---------------- generic NT-GEMM, bf16 MFMA, C stored [N][M] bf16 --------------
// MODE 0: plain; 1: *sM[m]; 2: relu(v*sN[b*sNstride+n] + bias[m])
template <int MODE>
__global__ __launch_bounds__(256) void k_gemm_nt(
    const short* __restrict__ A, const short* __restrict__ Bm, short* __restrict__ C,
    int K, int lda, int ldb, int ldc,
    size_t strideA, size_t strideB, size_t strideC,
    const float* __restrict__ sM, const float* __restrict__ sN, int sNstride,
    const float* __restrict__ bias) {
    const int b = blockIdx.z;
    const short* Ab = A + (size_t)b * strideA;
    const short* Bb = Bm + (size_t)b * strideB;
    short* Cb = C + (size_t)b * strideC;
    const int M0 = blockIdx.x * 128, N0 = blockIdx.y * 128;

    __shared__ __align__(16) short As[128 * 64];
    __shared__ __align__(16) short Bs[128 * 64];

    const int tid = threadIdx.x, lane = tid & 63, wid = tid >> 6;
    const int wm = (wid & 1) * 64, wn = (wid >> 1) * 64;
    const int r_in = lane >> 3, kc = lane & 7;

    f32x4 zero = {0.f, 0.f, 0.f, 0.f};
    f32x4 acc[4][4];
    #pragma unroll
    for (int mi = 0; mi < 4; ++mi)
        #pragma unroll
        for (int nj = 0; nj < 4; ++nj) acc[mi][nj] = zero;

    for (int kt = 0; kt < K; kt += 64) {
        #pragma unroll
        for (int q = 0; q < 4; ++q) {
            const int ch = wid * 4 + q;
            gl2lds16(Ab + (size_t)(M0 + ch * 8 + r_in) * lda + kt + kc * 8, &As[ch * 512]);
        }
        #pragma unroll
        for (int q = 0; q < 4; ++q) {
            const int ch = wid * 4 + q;
            gl2lds16(Bb + (size_t)(N0 + ch * 8 + r_in) * ldb + kt + kc * 8, &Bs[ch * 512]);
        }
        __syncthreads();
        #pragma unroll
        for (int kk = 0; kk < 2; ++kk) {
            bf16x8 af[4], bfr[4];
            const int co = kk * 32 + (lane >> 4) * 8;
            #pragma unroll
            for (int mi = 0; mi < 4; ++mi)
                af[mi] = *(const bf16x8*)&As[(wm + mi * 16 + (lane & 15)) * 64 + co];
            #pragma unroll
            for (int nj = 0; nj < 4; ++nj)
                bfr[nj] = *(const bf16x8*)&Bs[(wn + nj * 16 + (lane & 15)) * 64 + co];
            #pragma unroll
            for (int mi = 0; mi < 4; ++mi)
                #pragma unroll
                for (int nj = 0; nj < 4; ++nj)
                    acc[mi][nj] = __builtin_amdgcn_mfma_f32_16x16x32_bf16(
                        af[mi], bfr[nj], acc[mi][nj], 0, 0, 0);
        }
        __syncthreads();
    }

    #pragma unroll
    for (int mi = 0; mi < 4; ++mi) {
        const int m = M0 + wm + mi * 16 + (lane >> 4) * 4;
        float4 sm4 = make_float4(1.f, 1.f, 1.f, 1.f);
        float4 bs4 = make_float4(0.f, 0.f, 0.f, 0.f);
        if (MODE == 1) sm4 = *(const float4*)&sM[m];
        if (MODE == 2) bs4 = *(const float4*)&bias[m];
        #pragma unroll
        for (int nj = 0; nj < 4; ++nj) {
            const int n = N0 + wn + nj * 16 + (lane & 15);
            f32x4 v = acc[mi][nj];
            float o0 = v[0], o1 = v[1], o2 = v[2], o3 = v[3];
            if (MODE == 1) { o0 *= sm4.x; o1 *= sm4.y; o2 *= sm4.z; o3 *= sm4.w; }
            if (MODE == 2) {
                const float sn = sN[b * sNstride + n];
                o0 = fmaxf(o0 * sn + bs4.x, 0.f);
                o1 = fmaxf(o1 * sn + bs4.y, 0.f);
                o2 = fmaxf(o2 * sn + bs4.z, 0.f);
                o3 = fmaxf(o3 * sn + bs4.w, 0.f);
            }
            ushort4 o = make_ushort4(f2bf(o0), f2bf(o1), f2bf(o2), f2bf(o3));
            *(ushort4*)&Cb[(size_t)n * ldc + m] = o;
        }
    }
}

// ---------------- per-row softmax stats over Lbuf rows --------------------------
__global__ __launch_bounds__(256) void k_rowstat(const short* __restrict__ L,
                                                 float* __restrict__ rmax,
                                                 float* __restrict__ rsum) {
    const int row = blockIdx.x * 4 + (threadIdx.x >> 6);
    const int lane = threadIdx.x & 63;
    uint4 r = *(const uint4*)(L + (size_t)row * S + lane * 8);
    float v[8];
    unpack8(r, v);
    float mx = v[0];
    #pragma unroll
    for (int e = 1; e < 8; ++e) mx = fmaxf(mx, v[e]);
    #pragma unroll
    for (int off = 1; off < 64; off <<= 1) mx = fmaxf(mx, __shfl_xor(mx, off));
    float sm = 0.f;
    #pragma unroll
    for (int e = 0; e < 8; ++e) sm += __expf(v[e] - mx);
    #pragma unroll
    for (int off = 1; off < 64; off <<= 1) sm += __shfl_xor(sm, off);
    if (lane == 0) { rmax[row] = mx; rsum[row] = sm; }
}

// ---------------- build A_T[j][i] bf16 (threshold + self-loop) ------------------
__global__ __launch_bounds__(256) void k_buildAT(const short* __restrict__ L,
                                                 const float* __restrict__ rmax,
                                                 const float* __restrict__ rsum,
                                                 short* __restrict__ AT) {
    const int j = blockIdx.x * 4 + (threadIdx.x >> 6);  // global row of A_T
    const int lane = threadIdx.x & 63;
    const int b = j >> 9, jl = j & (S - 1);
    const size_t base = (size_t)b * S * S + (size_t)jl * S + lane * 8;
    uint4 r = *(const uint4*)(L + base);
    float v[8];
    unpack8(r, v);
    const int i0 = lane * 8;
    const float4 mxa = *(const float4*)&rmax[b * S + i0];
    const float4 mxb = *(const float4*)&rmax[b * S + i0 + 4];
    const float4 sma = *(const float4*)&rsum[b * S + i0];
    const float4 smb = *(const float4*)&rsum[b * S + i0 + 4];
    float mx[8] = {mxa.x, mxa.y, mxa.z, mxa.w, mxb.x, mxb.y, mxb.z, mxb.w};
    float sm[8] = {sma.x, sma.y, sma.z, sma.w, smb.x, smb.y, smb.z, smb.w};
    unsigned short o[8];
    #pragma unroll
    for (int e = 0; e < 8; ++e) {
        float att = __expf(v[e] - mx[e]) / sm[e];
        float a;
        if (i0 + e == jl) a = (att > THR) ? att : 1.0f;
        else              a = (att > THR) ? att : 0.0f;
        o[e] = f2bf(a);
    }
    uint4 w;
    w.x = (uint_t)o[0] | ((uint_t)o[1] << 16);
    w.y = (uint_t)o[2] | ((uint_t)o[3] << 16);
    w.z = (uint_t)o[4] | ((uint_t)o[5] << 16);
    w.w = (uint_t)o[6] | ((uint_t)o[7] << 16);
    *(uint4*)(AT + base) = w;
}

// ---------------- deg (row sums of A_T) -> dis, cvec ----------------------------
__global__ __launch_bounds__(256) void k_deg(const short* __restrict__ AT,
                                             const int* __restrict__ mask,
                                             float* __restrict__ dis,
                                             float* __restrict__ cvec) {
    const int r = blockIdx.x * 4 + (threadIdx.x >> 6);
    const int lane = threadIdx.x & 63;
    uint4 q = *(const uint4*)(AT + (size_t)r * S + lane * 8);
    float v[8];
    unpack8(q, v);
    float s = 0.f;
    #pragma unroll
    for (int e = 0; e < 8; ++e) s += v[e];
    #pragma unroll
    for (int off = 1; off < 64; off <<= 1) s += __shfl_xor(s, off);
    if (lane == 0) {
        float d = (s > 0.f) ? rsqrtf(s) : 0.f;
        dis[r] = d;
        cvec[r] = d * (float)mask[r];
    }
}

// ---------------- w[i] = dis_i * sum_j cvec[j] * A_T[j][i] ----------------------
__global__ __launch_bounds__(128) void k_w(const short* __restrict__ AT,
                                           const float* __restrict__ dis,
                                           const float* __restrict__ cvec,
                                           float* __restrict__ w) {
    const int i = blockIdx.x * 128 + threadIdx.x;
    const int b = blockIdx.y;
    const short* col = AT + (size_t)b * S * S + i;
    const float* cv = cvec + b * S;
    float acc = 0.f;
    #pragma unroll 8
    for (int j = 0; j < S; ++j) acc += bf2f((unsigned short)col[(size_t)j * S]) * cv[j];
    w[b * S + i] = acc * dis[b * S + i];
}

// ---------------- final: weighted colsum of xw2T + head -------------------------
__global__ __launch_bounds__(128) void k_final(const short* __restrict__ xw2T,
                                               const float* __restrict__ w,
                                               const int* __restrict__ mask,
                                               const float* __restrict__ b2,
                                               const float* __restrict__ Wc,
                                               const float* __restrict__ bc,
                                               float* __restrict__ out) {
    const int b = blockIdx.x;
    const int h = threadIdx.x;  // 0..127
    const short* xrow = xw2T + (size_t)h * (B * S) + b * S;
    const float* wb = w + b * S;
    const int* mb = mask + b * S;

    float acc = 0.f;
    for (int t = 0; t < S; t += 8) {
        uint4 r = *(const uint4*)&xrow[t];
        float v[8];
        unpack8(r, v);
        const float4 w0 = *(const float4*)&wb[t];
        const float4 w1 = *(const float4*)&wb[t + 4];
        acc += v[0] * w0.x + v[1] * w0.y + v[2] * w0.z + v[3] * w0.w;
        acc += v[4] * w1.x + v[5] * w1.y + v[6] * w1.z + v[7] * w1.w;
    }

    float msum = 0.f;
    for (int i = h; i < S; i += 128) msum += (float)mb[i];
    #pragma unroll
    for (int off = 1; off < 64; off <<= 1) msum += __shfl_xor(msum, off);
    __shared__ float redm[2], redv[2];
    if ((h & 63) == 0) redm[h >> 6] = msum;
    __syncthreads();
    msum = redm[0] + redm[1];

    const float e = b2[h] + acc / msum;
    float val = e * Wc[h];
    #pragma unroll
    for (int off = 1; off < 64; off <<= 1) val += __shfl_xor(val, off);
    if ((h & 63) == 0) redv[h >> 6] = val;
    __syncthreads();
    if (h == 0) {
        float z = redv[0] + redv[1] + bc[0];
        out[b] = 1.f / (1.f + expf(-z));
    }
}

extern "C" void kernel_launch(void* const* d_in, const int* in_sizes, int n_in,
                              void* d_out, int out_size, void* d_ws, size_t ws_size,
                              hipStream_t stream) {
    const float* H    = (const float*)d_in[0];
    const int*   mask = (const int*)d_in[1];
    const float* W1   = (const float*)d_in[2];
    const float* b1   = (const float*)d_in[3];
    const float* W2   = (const float*)d_in[4];
    const float* b2   = (const float*)d_in[5];
    const float* Wc   = (const float*)d_in[6];
    const float* bc   = (const float*)d_in[7];
    float* out = (float*)d_out;

    // workspace layout (bytes)
    char* wsb = (char*)d_ws;
    short* Hb    = (short*)(wsb);                       // 25165824 el = 50331648 B
    short* y1    = (short*)(wsb);                       // reuse after xw1 (8388608 el)
    short* xw2T  = (short*)(wsb + 16777216);            // 4194304 el (inside Hb region)
    short* Lbuf  = (short*)(wsb + 50331648);            // 16777216 el = 33554432 B
    short* xw1dT = (short*)(wsb + 50331648);            // reuse Lbuf region (8388608 el)
    short* AT    = (short*)(wsb + 83886080);            // 16777216 el = 33554432 B
    float* rmax  = (float*)(wsb + 117440512);           // 32768
    float* rsum  = rmax + 32768;
    float* dis   = rsum + 32768;
    float* cvec  = dis + 32768;
    float* wv    = cvec + 32768;
    short* W1T   = (short*)(wv + 32768);                // 196608 el
    short* W2T   = W1T + 196608;                        // 32768 el

    const int NTOK = B * S;  // 32768

    k_cast<<<2048, 256, 0, stream>>>(H, Hb, NTOK * D / 8);
    k_castT<<<768, 256, 0, stream>>>(W1, W1T, D, H1);
    k_castT<<<128, 256, 0, stream>>>(W2, W2T, H1, H2);

    // logits: per batch [S x S x D], out Lbuf[j][i] (= L, symmetric)
    k_gemm_nt<0><<<dim3(4, 4, B), 256, 0, stream>>>(
        Hb, Hb, Lbuf, D, D, D, S,
        (size_t)S * D, (size_t)S * D, (size_t)S * S, nullptr, nullptr, 0, nullptr);

    k_rowstat<<<NTOK / 4, 256, 0, stream>>>(Lbuf, rmax, rsum);
    k_buildAT<<<NTOK / 4, 256, 0, stream>>>(Lbuf, rmax, rsum, AT);
    k_deg<<<NTOK / 4, 256, 0, stream>>>(AT, mask, dis, cvec);
    k_w<<<dim3(S / 128, B), 128, 0, stream>>>(AT, dis, cvec, wv);

    // xw1dT[h1][tok] = dis_tok * (H @ W1)[tok][h1]   (M=NTOK, N=H1, K=D)
    k_gemm_nt<1><<<dim3(NTOK / 128, H1 / 128, 1), 256, 0, stream>>>(
        Hb, W1T, xw1dT, D, D, D, NTOK,
        0, 0, 0, dis, nullptr, 0, nullptr);

    // y1[tok][h1] = relu(dis_j * (xw1dT @ A_T^T) + b1)  (M=H1, N=S, K=S, batched)
    k_gemm_nt<2><<<dim3(H1 / 128, S / 128, B), 256, 0, stream>>>(
        xw1dT, AT, y1, S, NTOK, S, H1,
        (size_t)S, (size_t)S * S, (size_t)S * H1, nullptr, dis, S, b1);

    // xw2T[h2][tok] = (y1 @ W2)[tok][h2]   (M=NTOK, N=H2, K=H1)
    k_gemm_nt<0><<<dim3(NTOK / 128, H2 / 128, 1), 256, 0, stream>>>(
        y1, W2T, xw2T, H1, H1, H1, NTOK,
        0, 0, 0, nullptr, nullptr, 0, nullptr);

    k_final<<<B, 128, 0, stream>>>(xw2T, wv, mask, b2, Wc, bc, out);
}

// Round 3
// 184.262 us; speedup vs baseline: 4.4838x; 1.1281x over previous
//
#include <hip/hip_runtime.h>
#include <hip/hip_bf16.h>
#include <math.h>

constexpr int B = 64, S = 512, D = 768, H1 = 256, H2 = 128;
constexpr float THR = 0.1f;

typedef short bf16x8 __attribute__((ext_vector_type(8)));
typedef float f32x4 __attribute__((ext_vector_type(4)));
typedef unsigned int uint_t;
typedef const __attribute__((address_space(1))) unsigned int* gptr_t;
typedef __attribute__((address_space(3))) unsigned int* lptr_t;

__device__ __forceinline__ unsigned short f2bf(float f) {
    unsigned int u = __builtin_bit_cast(unsigned int, f);
    unsigned int r = (u + 0x7FFFu + ((u >> 16) & 1u)) >> 16;
    return (unsigned short)r;
}
__device__ __forceinline__ float bf2f(unsigned short b) {
    return __builtin_bit_cast(float, (unsigned int)b << 16);
}
__device__ __forceinline__ void unpack8(const uint4& r, float* v) {
    v[0] = __builtin_bit_cast(float, r.x << 16); v[1] = __builtin_bit_cast(float, r.x & 0xFFFF0000u);
    v[2] = __builtin_bit_cast(float, r.y << 16); v[3] = __builtin_bit_cast(float, r.y & 0xFFFF0000u);
    v[4] = __builtin_bit_cast(float, r.z << 16); v[5] = __builtin_bit_cast(float, r.z & 0xFFFF0000u);
    v[6] = __builtin_bit_cast(float, r.w << 16); v[7] = __builtin_bit_cast(float, r.w & 0xFFFF0000u);
}
__device__ __forceinline__ void gl2lds16(const void* g, void* l) {
    __builtin_amdgcn_global_load_lds((gptr_t)g, (lptr_t)l, 16, 0, 0);
}

// ---------------- cast H fp32 -> bf16 (row-major [tok][D]) ----------------
__global__ __launch_bounds__(256) void k_cast(const float* __restrict__ in,
                                              short* __restrict__ out, int n8) {
    for (int i = blockIdx.x * 256 + threadIdx.x; i < n8; i += gridDim.x * 256) {
        float4 a = ((const float4*)in)[i * 2];
        float4 b = ((const float4*)in)[i * 2 + 1];
        uint4 o;
        o.x = (uint_t)f2bf(a.x) | ((uint_t)f2bf(a.y) << 16);
        o.y = (uint_t)f2bf(a.z) | ((uint_t)f2bf(a.w) << 16);
        o.z = (uint_t)f2bf(b.x) | ((uint_t)f2bf(b.y) << 16);
        o.w = (uint_t)f2bf(b.z) | ((uint_t)f2bf(b.w) << 16);
        ((uint4*)out)[i] = o;
    }
}

// ---------------- cast + transpose weights: in[K][N] -> out[N][K] bf16 ----------
__global__ __launch_bounds__(256) void k_castT(const float* __restrict__ in,
                                               short* __restrict__ out, int Kd, int Nd) {
    int idx = blockIdx.x * 256 + threadIdx.x;
    if (idx >= Kd * Nd) return;
    int n = idx / Kd, k = idx - n * Kd;
    out[idx] = (short)f2bf(in[(size_t)k * Nd + n]);
}

// ---------------- symmetric logits: expL tiles + atomic row-sums ----------------
// Computes only upper-triangle 128x128 blocks (bi<=bj); stores exp(L) bf16 to both
// mirror locations; accumulates rsum[i] = sum_j exp(L[i][j]) via atomics.
__global__ __launch_bounds__(256) void k_logits_sym(const short* __restrict__ Hb_,
                                                    short* __restrict__ L,
                                                    float* __restrict__ rsum) {
    const int bz = blockIdx.z;
    int p = blockIdx.x, bi = 0;
    while (p >= 4 - bi) { p -= 4 - bi; ++bi; }
    const int bj = bi + p;
    const short* Ab = Hb_ + (size_t)bz * S * D;
    short* Lb = L + (size_t)bz * S * S;
    float* rs = rsum + bz * S;
    const int M0 = bi * 128, N0 = bj * 128;

    __shared__ __align__(16) short As[128 * 64];
    __shared__ __align__(16) short Bs[128 * 64];

    const int tid = threadIdx.x, lane = tid & 63, wid = tid >> 6;
    const int wm = (wid & 1) * 64, wn = (wid >> 1) * 64;
    const int r_in = lane >> 3, kc = lane & 7;

    f32x4 zero = {0.f, 0.f, 0.f, 0.f};
    f32x4 acc[4][4];
    #pragma unroll
    for (int mi = 0; mi < 4; ++mi)
        #pragma unroll
        for (int nj = 0; nj < 4; ++nj) acc[mi][nj] = zero;

    for (int kt = 0; kt < D; kt += 64) {
        #pragma unroll
        for (int q = 0; q < 4; ++q) {
            const int ch = wid * 4 + q;
            gl2lds16(Ab + (size_t)(M0 + ch * 8 + r_in) * D + kt + kc * 8, &As[ch * 512]);
        }
        #pragma unroll
        for (int q = 0; q < 4; ++q) {
            const int ch = wid * 4 + q;
            gl2lds16(Ab + (size_t)(N0 + ch * 8 + r_in) * D + kt + kc * 8, &Bs[ch * 512]);
        }
        __syncthreads();
        #pragma unroll
        for (int kk = 0; kk < 2; ++kk) {
            bf16x8 af[4], bfr[4];
            const int co = kk * 32 + (lane >> 4) * 8;
            #pragma unroll
            for (int mi = 0; mi < 4; ++mi)
                af[mi] = *(const bf16x8*)&As[(wm + mi * 16 + (lane & 15)) * 64 + co];
            #pragma unroll
            for (int nj = 0; nj < 4; ++nj)
                bfr[nj] = *(const bf16x8*)&Bs[(wn + nj * 16 + (lane & 15)) * 64 + co];
            #pragma unroll
            for (int mi = 0; mi < 4; ++mi)
                #pragma unroll
                for (int nj = 0; nj < 4; ++nj)
                    acc[mi][nj] = __builtin_amdgcn_mfma_f32_16x16x32_bf16(
                        af[mi], bfr[nj], acc[mi][nj], 0, 0, 0);
        }
        __syncthreads();
    }

    // exp in place
    #pragma unroll
    for (int mi = 0; mi < 4; ++mi)
        #pragma unroll
        for (int nj = 0; nj < 4; ++nj) {
            f32x4 v = acc[mi][nj];
            acc[mi][nj][0] = __expf(v[0]);
            acc[mi][nj][1] = __expf(v[1]);
            acc[mi][nj][2] = __expf(v[2]);
            acc[mi][nj][3] = __expf(v[3]);
        }

    // stores (standard [n][m]; mirror [m][n] for off-diag blocks)
    #pragma unroll
    for (int mi = 0; mi < 4; ++mi) {
        const int mb = M0 + wm + mi * 16 + (lane >> 4) * 4;
        #pragma unroll
        for (int nj = 0; nj < 4; ++nj) {
            const int n = N0 + wn + nj * 16 + (lane & 15);
            f32x4 v = acc[mi][nj];
            ushort4 o = make_ushort4(f2bf(v[0]), f2bf(v[1]), f2bf(v[2]), f2bf(v[3]));
            *(ushort4*)&Lb[(size_t)n * S + mb] = o;
            if (bi != bj) {
                Lb[(size_t)(mb + 0) * S + n] = (short)o.x;
                Lb[(size_t)(mb + 1) * S + n] = (short)o.y;
                Lb[(size_t)(mb + 2) * S + n] = (short)o.z;
                Lb[(size_t)(mb + 3) * S + n] = (short)o.w;
            }
        }
    }

    // col-partials: rsum[m] += sum over this tile's n
    #pragma unroll
    for (int mi = 0; mi < 4; ++mi)
        #pragma unroll
        for (int r = 0; r < 4; ++r) {
            float s = acc[mi][0][r] + acc[mi][1][r] + acc[mi][2][r] + acc[mi][3][r];
            s += __shfl_xor(s, 1); s += __shfl_xor(s, 2);
            s += __shfl_xor(s, 4); s += __shfl_xor(s, 8);
            if ((lane & 15) == 0)
                atomicAdd(&rs[M0 + wm + mi * 16 + (lane >> 4) * 4 + r], s);
        }
    // row-partials (mirror contribution): rsum[n] += sum over this tile's m
    if (bi != bj) {
        #pragma unroll
        for (int nj = 0; nj < 4; ++nj) {
            float s = 0.f;
            #pragma unroll
            for (int mi = 0; mi < 4; ++mi) {
                f32x4 v = acc[mi][nj];
                s += v[0] + v[1] + v[2] + v[3];
            }
            s += __shfl_xor(s, 16); s += __shfl_xor(s, 32);
            if (lane < 16)
                atomicAdd(&rs[N0 + wn + nj * 16 + lane], s);
        }
    }
}

// ---------------- fused: AT build + deg/dis + sparse w accumulation -------------
__global__ __launch_bounds__(256) void k_buildAT(const short* __restrict__ L,
                                                 const float* __restrict__ rsum,
                                                 const int* __restrict__ mask,
                                                 short* __restrict__ AT,
                                                 float* __restrict__ dis,
                                                 float* __restrict__ wacc) {
    const int j = blockIdx.x * 4 + (threadIdx.x >> 6);  // b*S + jl
    const int lane = threadIdx.x & 63;
    const int b = j >> 9, jl = j & (S - 1);
    const size_t base = (size_t)b * S * S + (size_t)jl * S + lane * 8;
    uint4 r = *(const uint4*)(L + base);
    float v[8];
    unpack8(r, v);
    const int i0 = lane * 8;
    const float4 sa = *(const float4*)&rsum[b * S + i0];
    const float4 sb = *(const float4*)&rsum[b * S + i0 + 4];
    const float rsv[8] = {sa.x, sa.y, sa.z, sa.w, sb.x, sb.y, sb.z, sb.w};
    float a[8];
    float deg = 0.f;
    #pragma unroll
    for (int e = 0; e < 8; ++e) {
        float att = v[e] / rsv[e];   // att[i][j], i = i0+e
        if (i0 + e == jl) a[e] = (att > THR) ? att : 1.0f;
        else              a[e] = (att > THR) ? att : 0.0f;
        deg += a[e];
    }
    // write AT row
    unsigned short o[8];
    #pragma unroll
    for (int e = 0; e < 8; ++e) o[e] = f2bf(a[e]);
    uint4 w;
    w.x = (uint_t)o[0] | ((uint_t)o[1] << 16);
    w.y = (uint_t)o[2] | ((uint_t)o[3] << 16);
    w.z = (uint_t)o[4] | ((uint_t)o[5] << 16);
    w.w = (uint_t)o[6] | ((uint_t)o[7] << 16);
    *(uint4*)(AT + base) = w;
    // deg reduce -> dis, cvec (all lanes)
    #pragma unroll
    for (int off = 1; off < 64; off <<= 1) deg += __shfl_xor(deg, off);
    const float d = (deg > 0.f) ? rsqrtf(deg) : 0.f;
    const float cv = d * (float)mask[j];
    if (lane == 0) dis[j] = d;
    // sparse w contribution: wacc[i] += cv * A[i][j]
    #pragma unroll
    for (int e = 0; e < 8; ++e)
        if (a[e] != 0.f) atomicAdd(&wacc[b * S + i0 + e], cv * a[e]);
}

// ---------------- generic NT-GEMM, bf16 MFMA, C stored [N][M] bf16 --------------
// MODE 0: plain; 1: *sM[m]; 2: relu(v*sN[b*sNstride+n] + bias[m])
template <int MODE>
__global__ __launch_bounds__(256) void k_gemm_nt(
    const short* __restrict__ A, const short* __restrict__ Bm, short* __restrict__ C,
    int K, int lda, int ldb, int ldc,
    size_t strideA, size_t strideB, size_t strideC,
    const float* __restrict__ sM, const float* __restrict__ sN, int sNstride,
    const float* __restrict__ bias) {
    const int b = blockIdx.z;
    const short* Ab = A + (size_t)b * strideA;
    const short* Bb = Bm + (size_t)b * strideB;
    short* Cb = C + (size_t)b * strideC;
    const int M0 = blockIdx.x * 128, N0 = blockIdx.y * 128;

    __shared__ __align__(16) short As[128 * 64];
    __shared__ __align__(16) short Bs[128 * 64];

    const int tid = threadIdx.x, lane = tid & 63, wid = tid >> 6;
    const int wm = (wid & 1) * 64, wn = (wid >> 1) * 64;
    const int r_in = lane >> 3, kc = lane & 7;

    f32x4 zero = {0.f, 0.f, 0.f, 0.f};
    f32x4 acc[4][4];
    #pragma unroll
    for (int mi = 0; mi < 4; ++mi)
        #pragma unroll
        for (int nj = 0; nj < 4; ++nj) acc[mi][nj] = zero;

    for (int kt = 0; kt < K; kt += 64) {
        #pragma unroll
        for (int q = 0; q < 4; ++q) {
            const int ch = wid * 4 + q;
            gl2lds16(Ab + (size_t)(M0 + ch * 8 + r_in) * lda + kt + kc * 8, &As[ch * 512]);
        }
        #pragma unroll
        for (int q = 0; q < 4; ++q) {
            const int ch = wid * 4 + q;
            gl2lds16(Bb + (size_t)(N0 + ch * 8 + r_in) * ldb + kt + kc * 8, &Bs[ch * 512]);
        }
        __syncthreads();
        #pragma unroll
        for (int kk = 0; kk < 2; ++kk) {
            bf16x8 af[4], bfr[4];
            const int co = kk * 32 + (lane >> 4) * 8;
            #pragma unroll
            for (int mi = 0; mi < 4; ++mi)
                af[mi] = *(const bf16x8*)&As[(wm + mi * 16 + (lane & 15)) * 64 + co];
            #pragma unroll
            for (int nj = 0; nj < 4; ++nj)
                bfr[nj] = *(const bf16x8*)&Bs[(wn + nj * 16 + (lane & 15)) * 64 + co];
            #pragma unroll
            for (int mi = 0; mi < 4; ++mi)
                #pragma unroll
                for (int nj = 0; nj < 4; ++nj)
                    acc[mi][nj] = __builtin_amdgcn_mfma_f32_16x16x32_bf16(
                        af[mi], bfr[nj], acc[mi][nj], 0, 0, 0);
        }
        __syncthreads();
    }

    #pragma unroll
    for (int mi = 0; mi < 4; ++mi) {
        const int m = M0 + wm + mi * 16 + (lane >> 4) * 4;
        float4 sm4 = make_float4(1.f, 1.f, 1.f, 1.f);
        float4 bs4 = make_float4(0.f, 0.f, 0.f, 0.f);
        if (MODE == 1) sm4 = *(const float4*)&sM[m];
        if (MODE == 2) bs4 = *(const float4*)&bias[m];
        #pragma unroll
        for (int nj = 0; nj < 4; ++nj) {
            const int n = N0 + wn + nj * 16 + (lane & 15);
            f32x4 v = acc[mi][nj];
            float o0 = v[0], o1 = v[1], o2 = v[2], o3 = v[3];
            if (MODE == 1) { o0 *= sm4.x; o1 *= sm4.y; o2 *= sm4.z; o3 *= sm4.w; }
            if (MODE == 2) {
                const float sn = sN[b * sNstride + n];
                o0 = fmaxf(o0 * sn + bs4.x, 0.f);
                o1 = fmaxf(o1 * sn + bs4.y, 0.f);
                o2 = fmaxf(o2 * sn + bs4.z, 0.f);
                o3 = fmaxf(o3 * sn + bs4.w, 0.f);
            }
            ushort4 o = make_ushort4(f2bf(o0), f2bf(o1), f2bf(o2), f2bf(o3));
            *(ushort4*)&Cb[(size_t)n * ldc + m] = o;
        }
    }
}

// ---------------- final: weighted colsum of xw2T + head -------------------------
__global__ __launch_bounds__(128) void k_final(const short* __restrict__ xw2T,
                                               const float* __restrict__ wacc,
                                               const float* __restrict__ dis,
                                               const int* __restrict__ mask,
                                               const float* __restrict__ b2,
                                               const float* __restrict__ Wc,
                                               const float* __restrict__ bc,
                                               float* __restrict__ out) {
    const int b = blockIdx.x;
    const int h = threadIdx.x;  // 0..127
    const short* xrow = xw2T + (size_t)h * (B * S) + b * S;
    const float* wa = wacc + b * S;
    const float* db = dis + b * S;
    const int* mb = mask + b * S;

    float acc = 0.f;
    for (int t = 0; t < S; t += 8) {
        uint4 r = *(const uint4*)&xrow[t];
        float v[8];
        unpack8(r, v);
        const float4 w0 = *(const float4*)&wa[t];
        const float4 w1 = *(const float4*)&wa[t + 4];
        const float4 d0 = *(const float4*)&db[t];
        const float4 d1 = *(const float4*)&db[t + 4];
        acc += v[0] * w0.x * d0.x + v[1] * w0.y * d0.y +
               v[2] * w0.z * d0.z + v[3] * w0.w * d0.w;
        acc += v[4] * w1.x * d1.x + v[5] * w1.y * d1.y +
               v[6] * w1.z * d1.z + v[7] * w1.w * d1.w;
    }

    float msum = 0.f;
    for (int i = h; i < S; i += 128) msum += (float)mb[i];
    #pragma unroll
    for (int off = 1; off < 64; off <<= 1) msum += __shfl_xor(msum, off);
    __shared__ float redm[2], redv[2];
    if ((h & 63) == 0) redm[h >> 6] = msum;
    __syncthreads();
    msum = redm[0] + redm[1];

    const float e = b2[h] + acc / msum;
    float val = e * Wc[h];
    #pragma unroll
    for (int off = 1; off < 64; off <<= 1) val += __shfl_xor(val, off);
    if ((h & 63) == 0) redv[h >> 6] = val;
    __syncthreads();
    if (h == 0) {
        float z = redv[0] + redv[1] + bc[0];
        out[b] = 1.f / (1.f + expf(-z));
    }
}

extern "C" void kernel_launch(void* const* d_in, const int* in_sizes, int n_in,
                              void* d_out, int out_size, void* d_ws, size_t ws_size,
                              hipStream_t stream) {
    const float* H    = (const float*)d_in[0];
    const int*   mask = (const int*)d_in[1];
    const float* W1   = (const float*)d_in[2];
    const float* b1   = (const float*)d_in[3];
    const float* W2   = (const float*)d_in[4];
    const float* b2   = (const float*)d_in[5];
    const float* Wc   = (const float*)d_in[6];
    const float* bc   = (const float*)d_in[7];
    float* out = (float*)d_out;

    const int NTOK = B * S;  // 32768

    // workspace layout (bytes)
    char* wsb = (char*)d_ws;
    short* Hb    = (short*)(wsb);                       // 25165824 el (48 MB)
    short* y1    = (short*)(wsb);                       // reuse (8388608 el, 16 MB)
    short* xw2T  = (short*)(wsb + 16777216);            // 4194304 el (8 MB)
    short* Lbuf  = (short*)(wsb + 50331648);            // 16777216 el (32 MB)
    short* xw1dT = (short*)(wsb + 50331648);            // reuse Lbuf (8388608 el)
    short* AT    = (short*)(wsb + 83886080);            // 16777216 el (32 MB)
    float* rsum  = (float*)(wsb + 117440512);           // 32768 f
    float* wacc  = rsum + NTOK;                         // 32768 f (contiguous w/ rsum)
    float* dis   = wacc + NTOK;                         // 32768 f
    short* W1T   = (short*)(dis + NTOK);                // 196608 el
    short* W2T   = W1T + 196608;                        // 32768 el

    hipMemsetAsync(rsum, 0, 2 * NTOK * sizeof(float), stream);  // rsum + wacc

    k_cast<<<2048, 256, 0, stream>>>(H, Hb, NTOK * D / 8);
    k_castT<<<768, 256, 0, stream>>>(W1, W1T, D, H1);
    k_castT<<<128, 256, 0, stream>>>(W2, W2T, H1, H2);

    // expL (symmetric, upper blocks) + row sums
    k_logits_sym<<<dim3(10, 1, B), 256, 0, stream>>>(Hb, Lbuf, rsum);

    // AT + dis + sparse w accumulation
    k_buildAT<<<NTOK / 4, 256, 0, stream>>>(Lbuf, rsum, mask, AT, dis, wacc);

    // xw1dT[h1][tok] = dis_tok * (H @ W1)[tok][h1]   (M=NTOK, N=H1, K=D)
    k_gemm_nt<1><<<dim3(NTOK / 128, H1 / 128, 1), 256, 0, stream>>>(
        Hb, W1T, xw1dT, D, D, D, NTOK,
        0, 0, 0, dis, nullptr, 0, nullptr);

    // y1[tok][h1] = relu(dis_j * (xw1dT @ AT^T) + b1)  (M=H1, N=S, K=S, batched)
    k_gemm_nt<2><<<dim3(H1 / 128, S / 128, B), 256, 0, stream>>>(
        xw1dT, AT, y1, S, NTOK, S, H1,
        (size_t)S, (size_t)S * S, (size_t)S * H1, nullptr, dis, S, b1);

    // xw2T[h2][tok] = (y1 @ W2)[tok][h2]   (M=NTOK, N=H2, K=H1)
    k_gemm_nt<0><<<dim3(NTOK / 128, H2 / 128, 1), 256, 0, stream>>>(
        y1, W2T, xw2T, H1, H1, H1, NTOK,
        0, 0, 0, nullptr, nullptr, 0, nullptr);

    k_final<<<B, 128, 0, stream>>>(xw2T, wacc, dis, mask, b2, Wc, bc, out);
}